// Round 2
// baseline (398.615 us; speedup 1.0000x reference)
//
#include <hip/hip_runtime.h>

#define Bn   64
#define Tn   2048
#define ENCD 512
#define DECD 1024
#define HIDD 128
#define TT   32
#define NCH  (Tn / TT)       // 64 chunks per batch
#define CPG  8               // chunks per group (per block)
#define NGR  (NCH / CPG)     // 8 groups per batch
#define LROW 520             // bf16 elems per LDS row: 512 + 8 pad

typedef __attribute__((ext_vector_type(8))) short bf16x8;
typedef __attribute__((ext_vector_type(4))) float f32x4;

__device__ __forceinline__ unsigned short f2bf(float f) {
    union { float f; unsigned u; } v; v.f = f;
    unsigned r = v.u + 0x7FFFu + ((v.u >> 16) & 1u);   // RNE
    return (unsigned short)(r >> 16);
}
__device__ __forceinline__ float bf2f(unsigned short s) {
    union { unsigned u; float f; } v; v.u = ((unsigned)s) << 16;
    return v.f;
}
__device__ __forceinline__ float tanh_fast(float x) {
    float xa = fminf(fmaxf(x, -10.f), 10.f);
    float e = __expf(2.f * xa);
    return (e - 1.f) / (e + 1.f);
}

// ---------------------------------------------------------------------------
// Kernel 1: qb[b][h] = dec[b]·W_w[h] + V_b[h]   and   Vbf = bf16(V_w)
// grid = 512 (GEMV) + 64 (convert), block = 256
// ---------------------------------------------------------------------------
__global__ __launch_bounds__(256) void prep(
    const float* __restrict__ dec, const float* __restrict__ Ww,
    const float* __restrict__ Vb,  const float* __restrict__ Vw,
    float* __restrict__ qb, unsigned short* __restrict__ Vbf)
{
    const int blk = blockIdx.x, tid = threadIdx.x;
    if (blk < 512) {
        // GEMV: block = (b, hg); 16 h per block, 16 lanes per h
        const int b = blk >> 3, hg = blk & 7;
        const int h_local = tid >> 4, seg = tid & 15;
        const int h = hg * 16 + h_local;
        const float4* w = (const float4*)(Ww + (size_t)h * DECD);
        const float4* d = (const float4*)(dec + (size_t)b * DECD);
        float acc = 0.f;
        #pragma unroll
        for (int j = 0; j < 16; ++j) {
            int f4 = j * 16 + seg;               // coalesced within 16-lane seg
            float4 a = d[f4], bb = w[f4];
            acc += a.x * bb.x + a.y * bb.y + a.z * bb.z + a.w * bb.w;
        }
        acc += __shfl_xor(acc, 1);
        acc += __shfl_xor(acc, 2);
        acc += __shfl_xor(acc, 4);
        acc += __shfl_xor(acc, 8);
        if (seg == 0) qb[b * HIDD + h] = acc + Vb[h];
    } else {
        // convert V_w (128x512 fp32 = 16384 float4) to bf16; 64 blocks x 256 f4
        const int c = blk - 512;                 // 0..63
        const float4* src = (const float4*)Vw;
        int f4 = c * 256 + tid;
        float4 v = src[f4];
        ushort4 u;
        u.x = f2bf(v.x); u.y = f2bf(v.y); u.z = f2bf(v.z); u.w = f2bf(v.w);
        *(ushort4*)&Vbf[f4 * 4] = u;
    }
}

// ---------------------------------------------------------------------------
// Kernel 2: persistent, double-buffered. grid = (NGR, Bn) = (8, 64) = 512
// blocks, block = 512 (8 waves). Each block owns CPG=8 consecutive chunks of
// one batch row: prefetch tile i+1 into regs while computing tile i; context
// accumulated online across the block's chunks (one ctxG write per block).
// LDS 67.7 KB -> exactly 2 blocks/CU resident (16 waves/CU, VGPR cap 128).
// ---------------------------------------------------------------------------
__global__ __launch_bounds__(512, 4) void attn_main(
    const float* __restrict__ enc, const int* __restrict__ mask,
    const float* __restrict__ qb,  const unsigned short* __restrict__ Vbf,
    const float* __restrict__ ww,  const float* __restrict__ wb,
    float* __restrict__ pW, float* __restrict__ mC, float* __restrict__ lC,
    float* __restrict__ ctxG, float* __restrict__ gmG)
{
    __shared__ unsigned short encS[2 * TT * LROW];   // 66560 B (double buffer)
    __shared__ float wpart[8][TT];                   // 1024 B
    __shared__ float pS[TT];                         // 128 B
    __shared__ float mS;                             // chunk max broadcast

    const int cg = blockIdx.x, b = blockIdx.y;
    const int tid = threadIdx.x;
    const int wave = tid >> 6, lane = tid & 63;
    const int li = lane & 15, quad = lane >> 4;

    // per-wave h column, loaded once
    const int h = wave * 16 + li;
    const float qv = qb[b * HIDD + h];
    const float wv = ww[h];
    const unsigned short* vrow = Vbf + (size_t)h * ENCD;

    const float4* encBase =
        (const float4*)(enc + ((size_t)b * Tn + (size_t)cg * (CPG * TT)) * ENCD);

    float4 v[8];
    // ---- prologue: stage tile 0 ----
    #pragma unroll
    for (int it = 0; it < 8; ++it) v[it] = encBase[it * 512 + tid];
    #pragma unroll
    for (int it = 0; it < 8; ++it) {
        int f4 = it * 512 + tid;
        int t = f4 >> 7, e2 = (f4 & 127) * 4;
        ushort4 u;
        u.x = f2bf(v[it].x); u.y = f2bf(v[it].y);
        u.z = f2bf(v[it].z); u.w = f2bf(v[it].w);
        *(ushort4*)&encS[t * LROW + e2] = u;
    }
    __syncthreads();

    float ctx = 0.f;          // online-accumulated context for e = tid
    float gm  = -INFINITY;    // running group max (uniform across block)

    for (int i = 0; i < CPG; ++i) {
        unsigned short* sb = encS + (i & 1) * (TT * LROW);
        const int chunk = cg * CPG + i;

        // ---- MFMA: k[t, h] for this wave's 16 h, all 32 t ----
        f32x4 acc[2];
        acc[0] = (f32x4){0.f, 0.f, 0.f, 0.f};
        acc[1] = (f32x4){0.f, 0.f, 0.f, 0.f};
        #pragma unroll 4
        for (int ks = 0; ks < 16; ++ks) {
            int k0 = ks * 32 + quad * 8;
            bf16x8 a0 = *(const bf16x8*)&sb[(0  + li) * LROW + k0];
            bf16x8 a1 = *(const bf16x8*)&sb[(16 + li) * LROW + k0];
            bf16x8 bb = *(const bf16x8*)(vrow + k0);
            acc[0] = __builtin_amdgcn_mfma_f32_16x16x32_bf16(a0, bb, acc[0], 0, 0, 0);
            acc[1] = __builtin_amdgcn_mfma_f32_16x16x32_bf16(a1, bb, acc[1], 0, 0, 0);
        }

        // ---- prefetch next tile into regs (issued AFTER the Vbf loads so
        //      their waitcnt doesn't drain the prefetch; consumed only at the
        //      LDS store below -> latency hides under epilogue/softmax/ctx) ----
        if (i + 1 < CPG) {
            #pragma unroll
            for (int it = 0; it < 8; ++it)
                v[it] = encBase[(i + 1) * (TT * ENCD / 4) + it * 512 + tid];
        }

        // ---- epilogue: s = tanh(k + q)*w_w; reduce over the wave's 16 h ----
        #pragma unroll
        for (int mt = 0; mt < 2; ++mt)
            #pragma unroll
            for (int r = 0; r < 4; ++r) {
                float s = tanh_fast(acc[mt][r] + qv) * wv;
                s += __shfl_xor(s, 1);
                s += __shfl_xor(s, 2);
                s += __shfl_xor(s, 4);
                s += __shfl_xor(s, 8);
                if (li == 0) wpart[wave][mt * 16 + quad * 4 + r] = s;
            }
        __syncthreads();

        // ---- wave 0: combine 8 wave partials, chunk softmax ----
        if (wave == 0) {
            float e = -INFINITY;
            if (lane < TT) {
                float vs = wb[0];
                #pragma unroll
                for (int w = 0; w < 8; ++w) vs += wpart[w][lane];
                e = (mask[b * Tn + chunk * TT + lane] != 0) ? -INFINITY : vs;
            }
            float m = e;
            #pragma unroll
            for (int off = 32; off >= 1; off >>= 1)
                m = fmaxf(m, __shfl_xor(m, off));
            float p = (e == -INFINITY) ? 0.f : __expf(e - m);
            float l = p;
            #pragma unroll
            for (int off = 32; off >= 1; off >>= 1)
                l += __shfl_xor(l, off);
            if (lane < TT) {
                pS[lane] = p;
                pW[(size_t)b * Tn + chunk * TT + lane] = p;
            }
            if (lane == 0) {
                mC[b * NCH + chunk] = m;
                lC[b * NCH + chunk] = l;
                mS = m;
            }
        }
        __syncthreads();

        // ---- online context accumulation: e = tid ----
        {
            const float m = mS;                  // uniform
            float sumt = 0.f;
            #pragma unroll
            for (int t = 0; t < TT; ++t)
                sumt += pS[t] * bf2f(sb[t * LROW + tid]);
            float nm = fmaxf(gm, m);
            if (nm > -INFINITY) {
                float rs = (gm > -INFINITY) ? __expf(gm - nm) : 0.f;
                float as = (m  > -INFINITY) ? __expf(m  - nm) : 0.f;
                ctx = ctx * rs + sumt * as;
                gm = nm;
            }
        }

        // ---- write next tile into the alternate LDS buffer ----
        if (i + 1 < CPG) {
            unsigned short* nb = encS + ((i + 1) & 1) * (TT * LROW);
            #pragma unroll
            for (int it = 0; it < 8; ++it) {
                int f4 = it * 512 + tid;
                int t = f4 >> 7, e2 = (f4 & 127) * 4;
                ushort4 u;
                u.x = f2bf(v[it].x); u.y = f2bf(v[it].y);
                u.z = f2bf(v[it].z); u.w = f2bf(v[it].w);
                *(ushort4*)&nb[t * LROW + e2] = u;
            }
        }
        __syncthreads();
    }

    // one context partial per block (group), plus the group max
    ctxG[((size_t)(b * NGR + cg)) * ENCD + tid] = ctx;
    if (tid == 0) gmG[b * NGR + cg] = gm;
}

// ---------------------------------------------------------------------------
// Kernel 3: combine.  grid = (Bn, 2), block = 512
//   part 0: context (512 e, sum over 8 group partials)
//   part 1: weights (2048 t, rescale per chunk)
// ---------------------------------------------------------------------------
__global__ __launch_bounds__(512) void finalize(
    const float* __restrict__ mC, const float* __restrict__ lC,
    const float* __restrict__ pW, const float* __restrict__ ctxG,
    const float* __restrict__ gmG, float* __restrict__ out)
{
    __shared__ float scaleS[NCH];
    __shared__ float invLs, GMs;
    const int b = blockIdx.x, part = blockIdx.y, tid = threadIdx.x;
    const int wave = tid >> 6, lane = tid & 63;

    if (wave == 0) {                             // NCH == 64 == wave width
        float m = mC[b * NCH + lane];
        float l = lC[b * NCH + lane];
        float gmax = m;
        #pragma unroll
        for (int off = 32; off >= 1; off >>= 1)
            gmax = fmaxf(gmax, __shfl_xor(gmax, off));
        float sc = (m == -INFINITY) ? 0.f : __expf(m - gmax);
        float ls = l * sc;
        #pragma unroll
        for (int off = 32; off >= 1; off >>= 1)
            ls += __shfl_xor(ls, off);
        scaleS[lane] = sc;
        if (lane == 0) { invLs = 1.f / ls; GMs = gmax; }
    }
    __syncthreads();
    const float invL = invLs;

    if (part == 0) {
        const float GM = GMs;
        float c = 0.f;
        #pragma unroll
        for (int g = 0; g < NGR; ++g) {
            float gmv = gmG[b * NGR + g];
            float gs = (gmv == -INFINITY) ? 0.f : __expf(gmv - GM);
            c += gs * ctxG[((size_t)(b * NGR + g)) * ENCD + tid];
        }
        out[b * ENCD + tid] = c * invL;
    } else {
        float* outw = out + Bn * ENCD;
        #pragma unroll
        for (int i = 0; i < 4; ++i) {
            int t = i * 512 + tid;
            outw[(size_t)b * Tn + t] = pW[(size_t)b * Tn + t] * scaleS[t >> 5] * invL;
        }
    }
}

// ---------------------------------------------------------------------------
extern "C" void kernel_launch(void* const* d_in, const int* in_sizes, int n_in,
                              void* d_out, int out_size, void* d_ws, size_t ws_size,
                              hipStream_t stream)
{
    const float* enc  = (const float*)d_in[0];
    const float* dec  = (const float*)d_in[1];
    const int*   mask = (const int*)d_in[2];
    const float* Vw   = (const float*)d_in[3];
    const float* Vb   = (const float*)d_in[4];
    const float* Ww   = (const float*)d_in[5];
    const float* ww   = (const float*)d_in[6];
    const float* wb   = (const float*)d_in[7];
    float* out = (float*)d_out;
    float* ws  = (float*)d_ws;

    // ws layout (float offsets) — Vbf is 65536 bf16 = 131072 B = 32768 floats:
    float*          qb   = ws;                               //      0 ..   8192
    unsigned short* Vbf  = (unsigned short*)(ws + 8192);     //   8192 ..  40960
    float*          pW   = ws + 40960;                       //  40960 .. 172032
    float*          mC   = ws + 172032;                      // 172032 .. 176128
    float*          lC   = ws + 176128;                      // 176128 .. 180224
    float*          ctxG = ws + 180224;                      // 180224 .. 442368 (64*8*512)
    float*          gmG  = ws + 442368;                      // 442368 .. 442880 (~1.77 MB)

    hipLaunchKernelGGL(prep, dim3(576), dim3(256), 0, stream, dec, Ww, Vb, Vw, qb, Vbf);
    hipLaunchKernelGGL(attn_main, dim3(NGR, Bn), dim3(512), 0, stream,
                       enc, mask, qb, Vbf, ww, wb, pW, mC, lC, ctxG, gmG);
    hipLaunchKernelGGL(finalize, dim3(Bn, 2), dim3(512), 0, stream, mC, lC, pW, ctxG, gmG, out);
}